// Round 16
// baseline (292.493 us; speedup 1.0000x reference)
//
#include <hip/hip_runtime.h>
#include <math.h>

#define EPSF 1e-5f
#define MAXN 0.95f
#define DD 128

typedef unsigned short u16;
typedef __attribute__((ext_vector_type(8))) __bf16 bf16x8;
typedef __attribute__((ext_vector_type(4))) float f32x4;
typedef __attribute__((ext_vector_type(8))) unsigned short u16x8;
typedef __attribute__((ext_vector_type(4))) unsigned u32x4;

#define MFMA16 __builtin_amdgcn_mfma_f32_16x16x32_bf16

// fp32 -> bf16 (RNE) and back
__device__ __forceinline__ u16 f2bf(float f) {
    unsigned u = __float_as_uint(f);
    return (u16)((u + 0x7FFFu + ((u >> 16) & 1u)) >> 16);
}
__device__ __forceinline__ float bf2f(u16 b) {
    return __uint_as_float(((unsigned)b) << 16);
}

// exp0 -> proj -> (optional log0) collapses to one scalar factor of the row.
__device__ __forceinline__ float chain_scale(float nrm, bool log_out) {
    float nc  = fmaxf(nrm, EPSF);
    float f   = tanhf(nc) / nc;
    float wn  = f * nrm;
    float p   = (wn > MAXN) ? (MAXN / fmaxf(wn, EPSF)) : 1.f;
    float s   = f * p;
    if (log_out) {
        float n2  = wn * p;
        float n2c = fmaxf(n2, EPSF);
        float arg = fminf(n2c, 1.f - EPSF);
        s *= atanhf(arg) / n2c;
    }
    return s;
}

// folded per-node aggregate scalar: chain(||sum||/cnt, log)/cnt
__device__ __forceinline__ float agg_scale(const float* __restrict__ ssum,
                                           const int* __restrict__ rowptr,
                                           int rg) {
    int cnt = max(rowptr[rg + 1] - rowptr[rg], 1);
    float inv = 1.f / (float)cnt;
    return chain_scale(sqrtf(ssum[rg]) * inv, true) * inv;
}

// ---- tiny zero-fill (hipMemsetAsync's fill kernel measured 42us for 208KB!)
__global__ __launch_bounds__(256)
void zero_int4(int4* __restrict__ p, int n4)
{
    int i = blockIdx.x * 256 + threadIdx.x;
    if (i < n4) p[i] = make_int4(0, 0, 0, 0);
}

// ---- prep: split weights into bf16 hi/lo planes (once per call) ------------
__global__ __launch_bounds__(256)
void split_w(const float* __restrict__ msgW, const float* __restrict__ updW,
             u16* __restrict__ whi, u16* __restrict__ wlo, int L)
{
    int gid = blockIdx.x * 256 + threadIdx.x;
    int total = L * 2 * DD * DD;
    if (gid >= total) return;
    int mat = gid >> 14;
    int elem = gid & (DD * DD - 1);
    int l = mat >> 1, tpe = mat & 1;
    float f = (tpe ? updW : msgW)[(size_t)l * DD * DD + elem];
    u16 hb = f2bf(f);
    whi[gid] = hb;
    wlo[gid] = f2bf(f - bf2f(hb));
}

// ---- MFMA linear: out = chain( (s_agg?)*v @ W^T + b ) ----------------------
// Activations bf16 hi-only; weights hi/lo split: 2-term v*Wh + v*Wl.
// Block = 4 waves, 32-node tile (mt=2); wave w owns cols [w*32, w*32+32).
template<int LOG_OUT, int FP32_OUT, int F32_IN, int SCALE_IN>
__global__ __launch_bounds__(256)
void mfma_linear(const u16* __restrict__ vhi, const float* __restrict__ xin,
                 const float* __restrict__ ssum, const int* __restrict__ rowptr,
                 const u16* __restrict__ whi, const u16* __restrict__ wlo,
                 const float* __restrict__ bias,
                 u16* __restrict__ ohi, float* __restrict__ ofp, int N)
{
    __shared__ float sred[4][32];
    __shared__ float sScale[32];
    __shared__ float sSin[SCALE_IN ? 32 : 1];
    __shared__ u16 sHi[FP32_OUT ? 1 : 32][136];

    const int tid  = threadIdx.x;
    const int w    = tid >> 6;
    const int lane = tid & 63;
    const int l15  = lane & 15, lk = lane >> 4;
    const int base = blockIdx.x * 32;

    if (SCALE_IN) {
        if (tid < 32) {
            int rg = base + tid;
            sSin[tid] = agg_scale(ssum, rowptr, rg < N ? rg : (N - 1));
        }
        __syncthreads();
    }

    bf16x8 wh[2][4], wl[2][4];
    #pragma unroll
    for (int nt = 0; nt < 2; ++nt) {
        const int j = w * 32 + nt * 16 + l15;
        #pragma unroll
        for (int kt = 0; kt < 4; ++kt) {
            const int off = j * DD + kt * 32 + lk * 8;
            wh[nt][kt] = *(const bf16x8*)(whi + off);
            wl[nt][kt] = *(const bf16x8*)(wlo + off);
        }
    }
    const float bv0 = bias[w * 32 + l15];
    const float bv1 = bias[w * 32 + 16 + l15];

    f32x4 acc[2][2];
    #pragma unroll
    for (int mt = 0; mt < 2; ++mt)
        #pragma unroll
        for (int nt = 0; nt < 2; ++nt)
            acc[mt][nt] = (f32x4){0.f, 0.f, 0.f, 0.f};

    #pragma unroll
    for (int mt = 0; mt < 2; ++mt) {
        int row = base + mt * 16 + l15;
        row = (row < N) ? row : (N - 1);
        bf16x8 ah[4];
        if (F32_IN) {
            const float* xr = xin + (size_t)row * DD + lk * 8;
            float fv[32];
            float ss = 0.f;
            #pragma unroll
            for (int kt = 0; kt < 4; ++kt) {
                float4 a = *(const float4*)(xr + kt * 32);
                float4 b = *(const float4*)(xr + kt * 32 + 4);
                fv[kt*8+0]=a.x; fv[kt*8+1]=a.y; fv[kt*8+2]=a.z; fv[kt*8+3]=a.w;
                fv[kt*8+4]=b.x; fv[kt*8+5]=b.y; fv[kt*8+6]=b.z; fv[kt*8+7]=b.w;
            }
            #pragma unroll
            for (int q = 0; q < 32; ++q) ss += fv[q] * fv[q];
            ss += __shfl_xor(ss, 16);
            ss += __shfl_xor(ss, 32);
            float nc = fmaxf(sqrtf(ss), EPSF);
            float sc = atanhf(fminf(nc, 1.f - EPSF)) / nc;
            #pragma unroll
            for (int kt = 0; kt < 4; ++kt) {
                u16x8 uh;
                #pragma unroll
                for (int q = 0; q < 8; ++q)
                    uh[q] = f2bf(fv[kt*8+q] * sc);
                ah[kt] = *reinterpret_cast<bf16x8*>(&uh);
            }
        } else {
            const size_t ro = (size_t)row * DD + lk * 8;
            #pragma unroll
            for (int kt = 0; kt < 4; ++kt)
                ah[kt] = *(const bf16x8*)(vhi + ro + kt * 32);
        }
        #pragma unroll
        for (int kt = 0; kt < 4; ++kt) {
            #pragma unroll
            for (int nt = 0; nt < 2; ++nt) {
                acc[mt][nt] = MFMA16(ah[kt], wh[nt][kt], acc[mt][nt], 0, 0, 0);
                acc[mt][nt] = MFMA16(ah[kt], wl[nt][kt], acc[mt][nt], 0, 0, 0);
            }
        }
    }

    #pragma unroll
    for (int mt = 0; mt < 2; ++mt) {
        #pragma unroll
        for (int r = 0; r < 4; ++r) {
            const float sv = SCALE_IN ? sSin[mt*16 + lk*4 + r] : 1.f;
            float y0 = acc[mt][0][r] * sv + bv0;
            float y1 = acc[mt][1][r] * sv + bv1;
            float part = y0 * y0 + y1 * y1;
            part += __shfl_xor(part, 1);
            part += __shfl_xor(part, 2);
            part += __shfl_xor(part, 4);
            part += __shfl_xor(part, 8);
            if (l15 == 0) sred[w][mt*16 + lk*4 + r] = part;
        }
    }
    __syncthreads();
    if (tid < 32) {
        float ss = sred[0][tid] + sred[1][tid] + sred[2][tid] + sred[3][tid];
        sScale[tid] = chain_scale(sqrtf(ss), LOG_OUT != 0);
    }
    __syncthreads();

    #pragma unroll
    for (int mt = 0; mt < 2; ++mt) {
        #pragma unroll
        for (int r = 0; r < 4; ++r) {
            const int rloc = mt*16 + lk*4 + r;
            const float s = sScale[rloc];
            const float sv = SCALE_IN ? sSin[rloc] : 1.f;
            #pragma unroll
            for (int nt = 0; nt < 2; ++nt) {
                float z = (acc[mt][nt][r] * sv + (nt ? bv1 : bv0)) * s;
                const int col = w*32 + nt*16 + l15;
                if (FP32_OUT) {
                    const int rg = base + rloc;
                    if (rg < N) ofp[(size_t)rg * DD + col] = z;
                } else {
                    sHi[rloc][col] = f2bf(z);
                }
            }
        }
    }
    if (!FP32_OUT) {
        __syncthreads();
        const int row = tid >> 3, qc = (tid & 7) * 16;
        const int rg = base + row;
        if (rg < N) {
            #pragma unroll
            for (int i = 0; i < 2; ++i)
                *(u16x8*)(ohi + (size_t)rg * DD + qc + i*8) =
                    *(const u16x8*)(&sHi[row][qc + i*8]);
        }
    }
}

// ---- FUSED mid-boundary: g_{l+1} = chain( chain( s*v@Wu^T + bu ) @ Wm^T + bm )
// 32-row tile (mt=2), ~10KB LDS.
__global__ __launch_bounds__(256)
void mfma_linear_fused(const u16* __restrict__ vhi,
                       const float* __restrict__ ssum, const int* __restrict__ rowptr,
                       const u16* __restrict__ wuh, const u16* __restrict__ wul,
                       const float* __restrict__ bu,
                       const u16* __restrict__ wmh, const u16* __restrict__ wml,
                       const float* __restrict__ bm,
                       u16* __restrict__ ohi, int N)
{
    __shared__ float sred[4][32];
    __shared__ float sScale[32];
    __shared__ float sSin[32];
    __shared__ u16 sHi[32][136];

    const int tid  = threadIdx.x;
    const int w    = tid >> 6;
    const int lane = tid & 63;
    const int l15  = lane & 15, lk = lane >> 4;
    const int base = blockIdx.x * 32;

    if (tid < 32) {
        int rg = base + tid;
        sSin[tid] = agg_scale(ssum, rowptr, rg < N ? rg : (N - 1));
    }
    __syncthreads();

    f32x4 acc[2][2];

    // ================= GEMM 1: t = chain( s*v @ Wu^T + bu ) =================
    {
        bf16x8 wh[2][4], wl[2][4];
        #pragma unroll
        for (int nt = 0; nt < 2; ++nt) {
            const int j = w * 32 + nt * 16 + l15;
            #pragma unroll
            for (int kt = 0; kt < 4; ++kt) {
                const int off = j * DD + kt * 32 + lk * 8;
                wh[nt][kt] = *(const bf16x8*)(wuh + off);
                wl[nt][kt] = *(const bf16x8*)(wul + off);
            }
        }
        const float bv0 = bu[w * 32 + l15];
        const float bv1 = bu[w * 32 + 16 + l15];

        #pragma unroll
        for (int mt = 0; mt < 2; ++mt)
            #pragma unroll
            for (int nt = 0; nt < 2; ++nt)
                acc[mt][nt] = (f32x4){0.f, 0.f, 0.f, 0.f};

        #pragma unroll
        for (int mt = 0; mt < 2; ++mt) {
            int row = base + mt * 16 + l15;
            row = (row < N) ? row : (N - 1);
            const size_t ro = (size_t)row * DD + lk * 8;
            bf16x8 ah[4];
            #pragma unroll
            for (int kt = 0; kt < 4; ++kt)
                ah[kt] = *(const bf16x8*)(vhi + ro + kt * 32);
            #pragma unroll
            for (int kt = 0; kt < 4; ++kt) {
                #pragma unroll
                for (int nt = 0; nt < 2; ++nt) {
                    acc[mt][nt] = MFMA16(ah[kt], wh[nt][kt], acc[mt][nt], 0, 0, 0);
                    acc[mt][nt] = MFMA16(ah[kt], wl[nt][kt], acc[mt][nt], 0, 0, 0);
                }
            }
        }

        #pragma unroll
        for (int mt = 0; mt < 2; ++mt) {
            #pragma unroll
            for (int r = 0; r < 4; ++r) {
                const float sv = sSin[mt*16 + lk*4 + r];
                float y0 = acc[mt][0][r] * sv + bv0;
                float y1 = acc[mt][1][r] * sv + bv1;
                float part = y0 * y0 + y1 * y1;
                part += __shfl_xor(part, 1);
                part += __shfl_xor(part, 2);
                part += __shfl_xor(part, 4);
                part += __shfl_xor(part, 8);
                if (l15 == 0) sred[w][mt*16 + lk*4 + r] = part;
            }
        }
        __syncthreads();
        if (tid < 32) {
            float ss = sred[0][tid] + sred[1][tid] + sred[2][tid] + sred[3][tid];
            sScale[tid] = chain_scale(sqrtf(ss), true);
        }
        __syncthreads();
        #pragma unroll
        for (int mt = 0; mt < 2; ++mt) {
            #pragma unroll
            for (int r = 0; r < 4; ++r) {
                const int rloc = mt*16 + lk*4 + r;
                const float s = sScale[rloc];
                const float sv = sSin[rloc];
                #pragma unroll
                for (int nt = 0; nt < 2; ++nt) {
                    float z = (acc[mt][nt][r] * sv + (nt ? bv1 : bv0)) * s;
                    sHi[rloc][w*32 + nt*16 + l15] = f2bf(z);
                }
            }
        }
    }
    __syncthreads();

    // ================= GEMM 2: g = chain( t @ Wm^T + bm ) ===================
    {
        bf16x8 wh[2][4], wl[2][4];
        #pragma unroll
        for (int nt = 0; nt < 2; ++nt) {
            const int j = w * 32 + nt * 16 + l15;
            #pragma unroll
            for (int kt = 0; kt < 4; ++kt) {
                const int off = j * DD + kt * 32 + lk * 8;
                wh[nt][kt] = *(const bf16x8*)(wmh + off);
                wl[nt][kt] = *(const bf16x8*)(wml + off);
            }
        }
        const float bv0 = bm[w * 32 + l15];
        const float bv1 = bm[w * 32 + 16 + l15];

        #pragma unroll
        for (int mt = 0; mt < 2; ++mt)
            #pragma unroll
            for (int nt = 0; nt < 2; ++nt)
                acc[mt][nt] = (f32x4){0.f, 0.f, 0.f, 0.f};

        #pragma unroll
        for (int mt = 0; mt < 2; ++mt) {
            const int r16 = mt * 16 + l15;
            bf16x8 ah[4];
            #pragma unroll
            for (int kt = 0; kt < 4; ++kt)
                ah[kt] = *(const bf16x8*)(&sHi[r16][kt * 32 + lk * 8]);
            #pragma unroll
            for (int kt = 0; kt < 4; ++kt) {
                #pragma unroll
                for (int nt = 0; nt < 2; ++nt) {
                    acc[mt][nt] = MFMA16(ah[kt], wh[nt][kt], acc[mt][nt], 0, 0, 0);
                    acc[mt][nt] = MFMA16(ah[kt], wl[nt][kt], acc[mt][nt], 0, 0, 0);
                }
            }
        }

        #pragma unroll
        for (int mt = 0; mt < 2; ++mt) {
            #pragma unroll
            for (int r = 0; r < 4; ++r) {
                float y0 = acc[mt][0][r] + bv0;
                float y1 = acc[mt][1][r] + bv1;
                float part = y0 * y0 + y1 * y1;
                part += __shfl_xor(part, 1);
                part += __shfl_xor(part, 2);
                part += __shfl_xor(part, 4);
                part += __shfl_xor(part, 8);
                if (l15 == 0) sred[w][mt*16 + lk*4 + r] = part;
            }
        }
        __syncthreads();
        if (tid < 32) {
            float ss = sred[0][tid] + sred[1][tid] + sred[2][tid] + sred[3][tid];
            sScale[tid] = chain_scale(sqrtf(ss), true);
        }
        __syncthreads();
        #pragma unroll
        for (int mt = 0; mt < 2; ++mt) {
            #pragma unroll
            for (int r = 0; r < 4; ++r) {
                const int rloc = mt*16 + lk*4 + r;
                const float s = sScale[rloc];
                #pragma unroll
                for (int nt = 0; nt < 2; ++nt) {
                    float z = (acc[mt][nt][r] + (nt ? bv1 : bv0)) * s;
                    sHi[rloc][w*32 + nt*16 + l15] = f2bf(z);
                }
            }
        }
        __syncthreads();
        const int row = tid >> 3, qc = (tid & 7) * 16;
        const int rg = base + row;
        if (rg < N) {
            #pragma unroll
            for (int i = 0; i < 2; ++i)
                *(u16x8*)(ohi + (size_t)rg * DD + qc + i*8) =
                    *(const u16x8*)(&sHi[row][qc + i*8]);
        }
    }
}

// ====== CSR build: contention-split atomics + single fused scan =============
__global__ __launch_bounds__(256)
void degree_rank4(const int* __restrict__ dst, int* __restrict__ cnt4,
                  int* __restrict__ rank, int E, int N)
{
    int e4 = (blockIdx.x * 256 + threadIdx.x) * 4;
    if (e4 + 3 < E) {
        int4 d = *(const int4*)(dst + e4);
        int4 r;
        r.x = atomicAdd(&cnt4[0 * N + d.x], 1);
        r.y = atomicAdd(&cnt4[1 * N + d.y], 1);
        r.z = atomicAdd(&cnt4[2 * N + d.z], 1);
        r.w = atomicAdd(&cnt4[3 * N + d.w], 1);
        *(int4*)(rank + e4) = r;
    } else {
        for (int e = e4; e < E; ++e)
            rank[e] = atomicAdd(&cnt4[(e & 3) * N + dst[e]], 1);
    }
}

// One block: deg = sum(cnt4), exclusive scan -> rowptr, bucket bases -> rpb.
// Requires cnt4 16B-aligned and N arbitrary (tail via masked scalar loads).
__global__ __launch_bounds__(1024)
void scan_fused(const int* __restrict__ cnt4, int* __restrict__ rowptr,
                int* __restrict__ rpb, int N)
{
    __shared__ int wsum[16];
    const int t = threadIdx.x, wv = t >> 6, ln = t & 63;
    int carry = 0;
    const int nch = (N + 4095) / 4096;
    for (int c = 0; c < nch; ++c) {
        const int i = c * 4096 + t * 4;
        int4 b0, b1, b2, b3;
        if (i + 3 < N) {
            b0 = *(const int4*)(cnt4 + 0 * N + i);
            b1 = *(const int4*)(cnt4 + 1 * N + i);
            b2 = *(const int4*)(cnt4 + 2 * N + i);
            b3 = *(const int4*)(cnt4 + 3 * N + i);
        } else {
            int v0[4], v1[4], v2[4], v3[4];
            #pragma unroll
            for (int q = 0; q < 4; ++q) {
                const int n = i + q;
                const bool ok = n < N;
                v0[q] = ok ? cnt4[0 * N + n] : 0;
                v1[q] = ok ? cnt4[1 * N + n] : 0;
                v2[q] = ok ? cnt4[2 * N + n] : 0;
                v3[q] = ok ? cnt4[3 * N + n] : 0;
            }
            b0 = make_int4(v0[0], v0[1], v0[2], v0[3]);
            b1 = make_int4(v1[0], v1[1], v1[2], v1[3]);
            b2 = make_int4(v2[0], v2[1], v2[2], v2[3]);
            b3 = make_int4(v3[0], v3[1], v3[2], v3[3]);
        }
        const int d0 = b0.x + b1.x + b2.x + b3.x;
        const int d1 = b0.y + b1.y + b2.y + b3.y;
        const int d2 = b0.z + b1.z + b2.z + b3.z;
        const int d3 = b0.w + b1.w + b2.w + b3.w;
        const int e1 = d0, e2 = e1 + d1, e3 = e2 + d2, tot = e3 + d3;
        int sc = tot;
        #pragma unroll
        for (int off = 1; off < 64; off <<= 1) {
            int u = __shfl_up(sc, off);
            if (ln >= off) sc += u;
        }
        if (ln == 63) wsum[wv] = sc;
        __syncthreads();
        if (wv == 0 && ln < 16) {
            int s2 = wsum[ln];
            #pragma unroll
            for (int off = 1; off < 16; off <<= 1) {
                int u = __shfl_up(s2, off);
                if (ln >= off) s2 += u;
            }
            wsum[ln] = s2;
        }
        __syncthreads();
        const int off0 = carry + ((wv > 0) ? wsum[wv - 1] : 0) + (sc - tot);
        const int rp[4]  = {off0, off0 + e1, off0 + e2, off0 + e3};
        const int c0v[4] = {b0.x, b0.y, b0.z, b0.w};
        const int c1v[4] = {b1.x, b1.y, b1.z, b1.w};
        const int c2v[4] = {b2.x, b2.y, b2.z, b2.w};
        #pragma unroll
        for (int q = 0; q < 4; ++q) {
            const int n = i + q;
            if (n < N) {
                rowptr[n]        = rp[q];
                rpb[0 * N + n]   = rp[q];
                rpb[1 * N + n]   = rp[q] + c0v[q];
                rpb[2 * N + n]   = rp[q] + c0v[q] + c1v[q];
                rpb[3 * N + n]   = rp[q] + c0v[q] + c1v[q] + c2v[q];
            }
        }
        carry += wsum[15];
        __syncthreads();
    }
    if (t == 0) rowptr[N] = carry;
}

__global__ __launch_bounds__(256)
void fill_csr4(const int* __restrict__ src, const int* __restrict__ dst,
               const int* __restrict__ rpb, const int* __restrict__ rank,
               int* __restrict__ csr, int E, int N)
{
    int e4 = (blockIdx.x * 256 + threadIdx.x) * 4;
    if (e4 + 3 < E) {
        int4 d = *(const int4*)(dst + e4);
        int4 r = *(const int4*)(rank + e4);
        int4 s = *(const int4*)(src + e4);
        csr[rpb[0 * N + d.x] + r.x] = s.x;
        csr[rpb[1 * N + d.y] + r.y] = s.y;
        csr[rpb[2 * N + d.z] + r.z] = s.z;
        csr[rpb[3 * N + d.w] + r.w] = s.w;
    } else {
        for (int e = e4; e < E; ++e)
            csr[rpb[(e & 3) * N + dst[e]] + rank[e]] = src[e];
    }
}

// ---- gather-SUM only: 1 wave/node, 4 edges x 16 lanes x 16B in flight ------
__global__ __launch_bounds__(256)
void csr_gather_sum(const u16* __restrict__ ghi, const int* __restrict__ rowptr,
                    const int* __restrict__ csr, u16* __restrict__ ohi,
                    float* __restrict__ ssum, int N)
{
    int node = blockIdx.x * 4 + (threadIdx.x >> 6);
    if (node >= N) return;
    const int lane = threadIdx.x & 63;
    const int eg = lane >> 4, l15 = lane & 15;
    const int beg = rowptr[node], end = rowptr[node + 1];

    float acc[8] = {0.f,0.f,0.f,0.f,0.f,0.f,0.f,0.f};
    for (int b = beg; b < end; b += 64) {
        const int cnt = min(end - b, 64);
        const int myidx = (lane < cnt) ? csr[b + lane] : 0;
        u32x4 vc;
        {
            const bool act = eg < cnt;
            const int s = __shfl(myidx, act ? eg : 0);
            if (act) vc = *(const u32x4*)(ghi + (size_t)s * DD + l15 * 8);
        }
        for (int j = 0; j < cnt; j += 4) {
            const int en = j + 4 + eg;
            const bool actn = en < cnt;
            const int sn = __shfl(myidx, actn ? en : 0);
            u32x4 vn;
            if (actn) vn = *(const u32x4*)(ghi + (size_t)sn * DD + l15 * 8);
            if (j + eg < cnt) {
                #pragma unroll
                for (int p = 0; p < 4; ++p) {
                    acc[2*p+0] += __uint_as_float(vc[p] << 16);
                    acc[2*p+1] += __uint_as_float(vc[p] & 0xffff0000u);
                }
            }
            vc = vn;
        }
    }
    #pragma unroll
    for (int q = 0; q < 8; ++q) {
        acc[q] += __shfl_xor(acc[q], 16);
        acc[q] += __shfl_xor(acc[q], 32);
    }
    float ss = 0.f;
    #pragma unroll
    for (int q = 0; q < 8; ++q) ss += acc[q] * acc[q];
    ss += __shfl_xor(ss, 1); ss += __shfl_xor(ss, 2);
    ss += __shfl_xor(ss, 4); ss += __shfl_xor(ss, 8);
    if (eg == 0) {
        u32x4 hw;
        #pragma unroll
        for (int p = 0; p < 4; ++p) {
            u16 h0 = f2bf(acc[2*p+0]), h1 = f2bf(acc[2*p+1]);
            hw[p] = (unsigned)h0 | ((unsigned)h1 << 16);
        }
        *(u32x4*)(ohi + (size_t)node * DD + l15 * 8) = hw;
        if (l15 == 0) ssum[node] = ss;
    }
}

extern "C" void kernel_launch(void* const* d_in, const int* in_sizes, int n_in,
                              void* d_out, int out_size, void* d_ws, size_t ws_size,
                              hipStream_t stream)
{
    const float* x     = (const float*)d_in[0];
    const int*   ei    = (const int*)d_in[1];
    const float* msg_W = (const float*)d_in[2];
    const float* msg_b = (const float*)d_in[3];
    const float* upd_W = (const float*)d_in[4];
    const float* upd_b = (const float*)d_in[5];

    const int N = in_sizes[0] / DD;
    const int E = in_sizes[1] / 2;
    const int L = in_sizes[2] / (DD * DD);

    const int* src = ei;
    const int* dst = ei + E;

    // ws layout (int4-aligned sections):
    // A (sum hi, N*DD u16) | W hi | W lo | rowptr(pad4) | csr(pad4) | ssum(pad4)
    // | cnt4 (4N, 16B-aligned) | rpb (4N)
    u16* Ahi  = (u16*)d_ws;
    u16* WhiA = Ahi + (size_t)N * DD;
    u16* WloA = WhiA + (size_t)2 * L * DD * DD;
    int* rowptr = (int*)(WloA + (size_t)2 * L * DD * DD);
    const size_t rowptrCap = ((size_t)(N + 1) + 3) & ~(size_t)3;
    int* csr  = rowptr + rowptrCap;
    const size_t csrCap = ((size_t)E + 3) & ~(size_t)3;
    float* ssum = (float*)(csr + csrCap);
    const size_t ssumCap = ((size_t)N + 3) & ~(size_t)3;
    int* cnt4 = (int*)(ssum + ssumCap);   // 16B-aligned by construction
    int* rpb  = cnt4 + 4 * (size_t)N;

    u16* Bhi  = (u16*)d_out;
    int* rank = (int*)(Bhi + (size_t)N * DD);   // borrowed during CSR build

    const int nodeBlocks  = (N + 31) / 32;
    const int aggBlocks   = (N + 3) / 4;
    const int edge4Blocks = ((E + 3) / 4 + 255) / 256;

    zero_int4<<<((4 * N) / 4 + 255) / 256, 256, 0, stream>>>((int4*)cnt4, (4 * N) / 4);
    degree_rank4<<<edge4Blocks, 256, 0, stream>>>(dst, cnt4, rank, E, N);
    scan_fused<<<1, 1024, 0, stream>>>(cnt4, rowptr, rpb, N);
    fill_csr4<<<edge4Blocks, 256, 0, stream>>>(src, dst, rpb, rank, csr, E, N);
    split_w<<<(2 * L * DD * DD + 255) / 256, 256, 0, stream>>>(
        msg_W, upd_W, WhiA, WloA, L);

    // K1 layer 0: g0 = chain(log0(x) @ Wm0^T + bm0) -> Bhi
    mfma_linear<1, 0, 1, 0><<<nodeBlocks, 256, 0, stream>>>(
        nullptr, x, nullptr, nullptr,
        WhiA, WloA, msg_b, Bhi, nullptr, N);

    for (int l = 0; l < L; ++l) {
        const u16* wuh = WhiA + (size_t)(l * 2 + 1) * DD * DD;
        const u16* wul = WloA + (size_t)(l * 2 + 1) * DD * DD;

        csr_gather_sum<<<aggBlocks, 256, 0, stream>>>(
            Bhi, rowptr, csr, Ahi, ssum, N);

        if (l < L - 1) {
            const u16* wmh = WhiA + (size_t)((l + 1) * 2 + 0) * DD * DD;
            const u16* wml = WloA + (size_t)((l + 1) * 2 + 0) * DD * DD;
            mfma_linear_fused<<<nodeBlocks, 256, 0, stream>>>(
                Ahi, ssum, rowptr,
                wuh, wul, upd_b + (size_t)l * DD,
                wmh, wml, msg_b + (size_t)(l + 1) * DD,
                Bhi, N);
        } else {
            mfma_linear<0, 1, 0, 1><<<nodeBlocks, 256, 0, stream>>>(
                Ahi, nullptr, ssum, rowptr,
                wuh, wul, upd_b + (size_t)l * DD,
                nullptr, (float*)d_out, N);
        }
    }
}

// Round 17
// 237.261 us; speedup vs baseline: 1.2328x; 1.2328x over previous
//
#include <hip/hip_runtime.h>
#include <math.h>

#define EPSF 1e-5f
#define MAXN 0.95f
#define DD 128

typedef unsigned short u16;
typedef __attribute__((ext_vector_type(8))) __bf16 bf16x8;
typedef __attribute__((ext_vector_type(4))) float f32x4;
typedef __attribute__((ext_vector_type(8))) unsigned short u16x8;
typedef __attribute__((ext_vector_type(4))) unsigned u32x4;

#define MFMA16 __builtin_amdgcn_mfma_f32_16x16x32_bf16

// fp32 -> bf16 (RNE) and back
__device__ __forceinline__ u16 f2bf(float f) {
    unsigned u = __float_as_uint(f);
    return (u16)((u + 0x7FFFu + ((u >> 16) & 1u)) >> 16);
}
__device__ __forceinline__ float bf2f(u16 b) {
    return __uint_as_float(((unsigned)b) << 16);
}

// exp0 -> proj -> (optional log0) collapses to one scalar factor of the row.
__device__ __forceinline__ float chain_scale(float nrm, bool log_out) {
    float nc  = fmaxf(nrm, EPSF);
    float f   = tanhf(nc) / nc;
    float wn  = f * nrm;
    float p   = (wn > MAXN) ? (MAXN / fmaxf(wn, EPSF)) : 1.f;
    float s   = f * p;
    if (log_out) {
        float n2  = wn * p;
        float n2c = fmaxf(n2, EPSF);
        float arg = fminf(n2c, 1.f - EPSF);
        s *= atanhf(arg) / n2c;
    }
    return s;
}

// folded per-node aggregate scalar: chain(||sum||/cnt, log)/cnt
__device__ __forceinline__ float agg_scale(const float* __restrict__ ssum,
                                           const int* __restrict__ rowptr,
                                           int rg) {
    int cnt = max(rowptr[rg + 1] - rowptr[rg], 1);
    float inv = 1.f / (float)cnt;
    return chain_scale(sqrtf(ssum[rg]) * inv, true) * inv;
}

// ---- tiny zero-fill (hipMemsetAsync's fill kernel measured 42us for 208KB!)
__global__ __launch_bounds__(256)
void zero_int4(int4* __restrict__ p, int n4)
{
    int i = blockIdx.x * 256 + threadIdx.x;
    if (i < n4) p[i] = make_int4(0, 0, 0, 0);
}

// ---- prep: split weights into bf16 hi/lo planes (once per call) ------------
__global__ __launch_bounds__(256)
void split_w(const float* __restrict__ msgW, const float* __restrict__ updW,
             u16* __restrict__ whi, u16* __restrict__ wlo, int L)
{
    int gid = blockIdx.x * 256 + threadIdx.x;
    int total = L * 2 * DD * DD;
    if (gid >= total) return;
    int mat = gid >> 14;
    int elem = gid & (DD * DD - 1);
    int l = mat >> 1, tpe = mat & 1;
    float f = (tpe ? updW : msgW)[(size_t)l * DD * DD + elem];
    u16 hb = f2bf(f);
    whi[gid] = hb;
    wlo[gid] = f2bf(f - bf2f(hb));
}

// ---- MFMA linear: out = chain( (s_agg?)*v @ W^T + b ) ----------------------
// Activations bf16 hi-only; weights hi/lo split: 2-term v*Wh + v*Wl.
// Block = 4 waves, 64-node tile; wave w owns output cols [w*32, w*32+32).
template<int LOG_OUT, int FP32_OUT, int F32_IN, int SCALE_IN>
__global__ __launch_bounds__(256)
void mfma_linear(const u16* __restrict__ vhi, const float* __restrict__ xin,
                 const float* __restrict__ ssum, const int* __restrict__ rowptr,
                 const u16* __restrict__ whi, const u16* __restrict__ wlo,
                 const float* __restrict__ bias,
                 u16* __restrict__ ohi, float* __restrict__ ofp, int N)
{
    __shared__ float sred[4][64];
    __shared__ float sScale[64];
    __shared__ float sSin[SCALE_IN ? 64 : 1];
    __shared__ u16 sHi[FP32_OUT ? 1 : 64][136];

    const int tid  = threadIdx.x;
    const int w    = tid >> 6;
    const int lane = tid & 63;
    const int l15  = lane & 15, lk = lane >> 4;
    const int base = blockIdx.x * 64;

    if (SCALE_IN) {
        if (tid < 64) {
            int rg = base + tid;
            sSin[tid] = agg_scale(ssum, rowptr, rg < N ? rg : (N - 1));
        }
        __syncthreads();
    }

    bf16x8 wh[2][4], wl[2][4];
    #pragma unroll
    for (int nt = 0; nt < 2; ++nt) {
        const int j = w * 32 + nt * 16 + l15;
        #pragma unroll
        for (int kt = 0; kt < 4; ++kt) {
            const int off = j * DD + kt * 32 + lk * 8;
            wh[nt][kt] = *(const bf16x8*)(whi + off);
            wl[nt][kt] = *(const bf16x8*)(wlo + off);
        }
    }
    const float bv0 = bias[w * 32 + l15];
    const float bv1 = bias[w * 32 + 16 + l15];

    f32x4 acc[4][2];
    #pragma unroll
    for (int mt = 0; mt < 4; ++mt)
        #pragma unroll
        for (int nt = 0; nt < 2; ++nt)
            acc[mt][nt] = (f32x4){0.f, 0.f, 0.f, 0.f};

    #pragma unroll
    for (int mt = 0; mt < 4; ++mt) {
        int row = base + mt * 16 + l15;
        row = (row < N) ? row : (N - 1);          // clamp pad rows (not stored)
        bf16x8 ah[4];
        if (F32_IN) {
            // fp32 row + in-register log0: lanes {l15 fixed, lk 0..3} hold row
            const float* xr = xin + (size_t)row * DD + lk * 8;
            float fv[32];
            float ss = 0.f;
            #pragma unroll
            for (int kt = 0; kt < 4; ++kt) {
                float4 a = *(const float4*)(xr + kt * 32);
                float4 b = *(const float4*)(xr + kt * 32 + 4);
                fv[kt*8+0]=a.x; fv[kt*8+1]=a.y; fv[kt*8+2]=a.z; fv[kt*8+3]=a.w;
                fv[kt*8+4]=b.x; fv[kt*8+5]=b.y; fv[kt*8+6]=b.z; fv[kt*8+7]=b.w;
            }
            #pragma unroll
            for (int q = 0; q < 32; ++q) ss += fv[q] * fv[q];
            ss += __shfl_xor(ss, 16);
            ss += __shfl_xor(ss, 32);
            float nc = fmaxf(sqrtf(ss), EPSF);
            float sc = atanhf(fminf(nc, 1.f - EPSF)) / nc;
            #pragma unroll
            for (int kt = 0; kt < 4; ++kt) {
                u16x8 uh;
                #pragma unroll
                for (int q = 0; q < 8; ++q)
                    uh[q] = f2bf(fv[kt*8+q] * sc);
                ah[kt] = *reinterpret_cast<bf16x8*>(&uh);
            }
        } else {
            const size_t ro = (size_t)row * DD + lk * 8;
            #pragma unroll
            for (int kt = 0; kt < 4; ++kt)
                ah[kt] = *(const bf16x8*)(vhi + ro + kt * 32);
        }
        #pragma unroll
        for (int kt = 0; kt < 4; ++kt) {
            #pragma unroll
            for (int nt = 0; nt < 2; ++nt) {
                acc[mt][nt] = MFMA16(ah[kt], wh[nt][kt], acc[mt][nt], 0, 0, 0);
                acc[mt][nt] = MFMA16(ah[kt], wl[nt][kt], acc[mt][nt], 0, 0, 0);
            }
        }
    }

    // ---- epilogue: per-row norm (cross-wave), one chain_scale per row ------
    #pragma unroll
    for (int mt = 0; mt < 4; ++mt) {
        #pragma unroll
        for (int r = 0; r < 4; ++r) {
            const float sv = SCALE_IN ? sSin[mt*16 + lk*4 + r] : 1.f;
            float y0 = acc[mt][0][r] * sv + bv0;
            float y1 = acc[mt][1][r] * sv + bv1;
            float part = y0 * y0 + y1 * y1;
            part += __shfl_xor(part, 1);
            part += __shfl_xor(part, 2);
            part += __shfl_xor(part, 4);
            part += __shfl_xor(part, 8);
            if (l15 == 0) sred[w][mt*16 + lk*4 + r] = part;
        }
    }
    __syncthreads();
    if (tid < 64) {
        float ss = sred[0][tid] + sred[1][tid] + sred[2][tid] + sred[3][tid];
        sScale[tid] = chain_scale(sqrtf(ss), LOG_OUT != 0);
    }
    __syncthreads();

    #pragma unroll
    for (int mt = 0; mt < 4; ++mt) {
        #pragma unroll
        for (int r = 0; r < 4; ++r) {
            const int rloc = mt*16 + lk*4 + r;
            const float s = sScale[rloc];
            const float sv = SCALE_IN ? sSin[rloc] : 1.f;
            #pragma unroll
            for (int nt = 0; nt < 2; ++nt) {
                float z = (acc[mt][nt][r] * sv + (nt ? bv1 : bv0)) * s;
                const int col = w*32 + nt*16 + l15;
                if (FP32_OUT) {
                    const int rg = base + rloc;
                    if (rg < N) ofp[(size_t)rg * DD + col] = z;
                } else {
                    sHi[rloc][col] = f2bf(z);
                }
            }
        }
    }
    if (!FP32_OUT) {
        __syncthreads();
        const int row = tid >> 2, qc = (tid & 3) * 32;
        const int rg = base + row;
        if (rg < N) {
            #pragma unroll
            for (int i = 0; i < 4; ++i)
                *(u16x8*)(ohi + (size_t)rg * DD + qc + i*8) =
                    *(const u16x8*)(&sHi[row][qc + i*8]);
        }
    }
}

// ---- FUSED mid-boundary: g_{l+1} = chain( chain( s*v@Wu^T + bu ) @ Wm^T + bm )
// 2-term GEMMs; t staged bf16-hi in LDS (17.4KB).
__global__ __launch_bounds__(256)
void mfma_linear_fused(const u16* __restrict__ vhi,
                       const float* __restrict__ ssum, const int* __restrict__ rowptr,
                       const u16* __restrict__ wuh, const u16* __restrict__ wul,
                       const float* __restrict__ bu,
                       const u16* __restrict__ wmh, const u16* __restrict__ wml,
                       const float* __restrict__ bm,
                       u16* __restrict__ ohi, int N)
{
    __shared__ float sred[4][64];
    __shared__ float sScale[64];
    __shared__ float sSin[64];
    __shared__ u16 sHi[64][136];     // t (then g) staging, hi plane only

    const int tid  = threadIdx.x;
    const int w    = tid >> 6;
    const int lane = tid & 63;
    const int l15  = lane & 15, lk = lane >> 4;
    const int base = blockIdx.x * 64;

    if (tid < 64) {
        int rg = base + tid;
        sSin[tid] = agg_scale(ssum, rowptr, rg < N ? rg : (N - 1));
    }
    __syncthreads();

    f32x4 acc[4][2];

    // ================= GEMM 1: t = chain( s*v @ Wu^T + bu ) =================
    {
        bf16x8 wh[2][4], wl[2][4];
        #pragma unroll
        for (int nt = 0; nt < 2; ++nt) {
            const int j = w * 32 + nt * 16 + l15;
            #pragma unroll
            for (int kt = 0; kt < 4; ++kt) {
                const int off = j * DD + kt * 32 + lk * 8;
                wh[nt][kt] = *(const bf16x8*)(wuh + off);
                wl[nt][kt] = *(const bf16x8*)(wul + off);
            }
        }
        const float bv0 = bu[w * 32 + l15];
        const float bv1 = bu[w * 32 + 16 + l15];

        #pragma unroll
        for (int mt = 0; mt < 4; ++mt)
            #pragma unroll
            for (int nt = 0; nt < 2; ++nt)
                acc[mt][nt] = (f32x4){0.f, 0.f, 0.f, 0.f};

        #pragma unroll
        for (int mt = 0; mt < 4; ++mt) {
            int row = base + mt * 16 + l15;
            row = (row < N) ? row : (N - 1);
            const size_t ro = (size_t)row * DD + lk * 8;
            bf16x8 ah[4];
            #pragma unroll
            for (int kt = 0; kt < 4; ++kt)
                ah[kt] = *(const bf16x8*)(vhi + ro + kt * 32);
            #pragma unroll
            for (int kt = 0; kt < 4; ++kt) {
                #pragma unroll
                for (int nt = 0; nt < 2; ++nt) {
                    acc[mt][nt] = MFMA16(ah[kt], wh[nt][kt], acc[mt][nt], 0, 0, 0);
                    acc[mt][nt] = MFMA16(ah[kt], wl[nt][kt], acc[mt][nt], 0, 0, 0);
                }
            }
        }

        // epilogue 1: row norms -> chain (log) -> stage t-hi in LDS
        #pragma unroll
        for (int mt = 0; mt < 4; ++mt) {
            #pragma unroll
            for (int r = 0; r < 4; ++r) {
                const float sv = sSin[mt*16 + lk*4 + r];
                float y0 = acc[mt][0][r] * sv + bv0;
                float y1 = acc[mt][1][r] * sv + bv1;
                float part = y0 * y0 + y1 * y1;
                part += __shfl_xor(part, 1);
                part += __shfl_xor(part, 2);
                part += __shfl_xor(part, 4);
                part += __shfl_xor(part, 8);
                if (l15 == 0) sred[w][mt*16 + lk*4 + r] = part;
            }
        }
        __syncthreads();
        if (tid < 64) {
            float ss = sred[0][tid] + sred[1][tid] + sred[2][tid] + sred[3][tid];
            sScale[tid] = chain_scale(sqrtf(ss), true);
        }
        __syncthreads();
        #pragma unroll
        for (int mt = 0; mt < 4; ++mt) {
            #pragma unroll
            for (int r = 0; r < 4; ++r) {
                const int rloc = mt*16 + lk*4 + r;
                const float s = sScale[rloc];
                const float sv = sSin[rloc];
                #pragma unroll
                for (int nt = 0; nt < 2; ++nt) {
                    float z = (acc[mt][nt][r] * sv + (nt ? bv1 : bv0)) * s;
                    sHi[rloc][w*32 + nt*16 + l15] = f2bf(z);
                }
            }
        }
    }
    __syncthreads();

    // ================= GEMM 2: g = chain( t @ Wm^T + bm ) ===================
    {
        bf16x8 wh[2][4], wl[2][4];
        #pragma unroll
        for (int nt = 0; nt < 2; ++nt) {
            const int j = w * 32 + nt * 16 + l15;
            #pragma unroll
            for (int kt = 0; kt < 4; ++kt) {
                const int off = j * DD + kt * 32 + lk * 8;
                wh[nt][kt] = *(const bf16x8*)(wmh + off);
                wl[nt][kt] = *(const bf16x8*)(wml + off);
            }
        }
        const float bv0 = bm[w * 32 + l15];
        const float bv1 = bm[w * 32 + 16 + l15];

        #pragma unroll
        for (int mt = 0; mt < 4; ++mt)
            #pragma unroll
            for (int nt = 0; nt < 2; ++nt)
                acc[mt][nt] = (f32x4){0.f, 0.f, 0.f, 0.f};

        #pragma unroll
        for (int mt = 0; mt < 4; ++mt) {
            const int r16 = mt * 16 + l15;
            bf16x8 ah[4];
            #pragma unroll
            for (int kt = 0; kt < 4; ++kt)
                ah[kt] = *(const bf16x8*)(&sHi[r16][kt * 32 + lk * 8]);
            #pragma unroll
            for (int kt = 0; kt < 4; ++kt) {
                #pragma unroll
                for (int nt = 0; nt < 2; ++nt) {
                    acc[mt][nt] = MFMA16(ah[kt], wh[nt][kt], acc[mt][nt], 0, 0, 0);
                    acc[mt][nt] = MFMA16(ah[kt], wl[nt][kt], acc[mt][nt], 0, 0, 0);
                }
            }
        }

        // epilogue 2: row norms -> chain (log) -> write g hi plane
        #pragma unroll
        for (int mt = 0; mt < 4; ++mt) {
            #pragma unroll
            for (int r = 0; r < 4; ++r) {
                float y0 = acc[mt][0][r] + bv0;
                float y1 = acc[mt][1][r] + bv1;
                float part = y0 * y0 + y1 * y1;
                part += __shfl_xor(part, 1);
                part += __shfl_xor(part, 2);
                part += __shfl_xor(part, 4);
                part += __shfl_xor(part, 8);
                if (l15 == 0) sred[w][mt*16 + lk*4 + r] = part;
            }
        }
        __syncthreads();
        if (tid < 64) {
            float ss = sred[0][tid] + sred[1][tid] + sred[2][tid] + sred[3][tid];
            sScale[tid] = chain_scale(sqrtf(ss), true);
        }
        __syncthreads();
        #pragma unroll
        for (int mt = 0; mt < 4; ++mt) {
            #pragma unroll
            for (int r = 0; r < 4; ++r) {
                const int rloc = mt*16 + lk*4 + r;
                const float s = sScale[rloc];
                #pragma unroll
                for (int nt = 0; nt < 2; ++nt) {
                    float z = (acc[mt][nt][r] + (nt ? bv1 : bv0)) * s;
                    sHi[rloc][w*32 + nt*16 + l15] = f2bf(z);
                }
            }
        }
        __syncthreads();
        const int row = tid >> 2, qc = (tid & 3) * 32;
        const int rg = base + row;
        if (rg < N) {
            #pragma unroll
            for (int i = 0; i < 4; ++i)
                *(u16x8*)(ohi + (size_t)rg * DD + qc + i*8) =
                    *(const u16x8*)(&sHi[row][qc + i*8]);
        }
    }
}

// ---------------- CSR build (edge list is layer-invariant) -------------------
__global__ __launch_bounds__(256)
void degree_rank(const int* __restrict__ dst, int* __restrict__ deg,
                 int* __restrict__ rank, int E)
{
    int e4 = (blockIdx.x * 256 + threadIdx.x) * 4;
    if (e4 + 3 < E) {
        int4 d = *(const int4*)(dst + e4);
        int4 r;
        r.x = atomicAdd(&deg[d.x], 1);
        r.y = atomicAdd(&deg[d.y], 1);
        r.z = atomicAdd(&deg[d.z], 1);
        r.w = atomicAdd(&deg[d.w], 1);
        *(int4*)(rank + e4) = r;
    } else {
        for (int e = e4; e < E; ++e) rank[e] = atomicAdd(&deg[dst[e]], 1);
    }
}

__global__ __launch_bounds__(1024)
void scan_rowptr(const int* __restrict__ deg, int* __restrict__ rowptr, int N)
{
    __shared__ int wsum[16];
    const int t = threadIdx.x, wv = t >> 6, ln = t & 63;
    int carry = 0;
    const int nch = (N + 4095) / 4096;
    for (int c = 0; c < nch; ++c) {
        const int i = c * 4096 + t * 4;
        int4 d = *(const int4*)(deg + i);
        int e1 = d.x, e2 = e1 + d.y, e3 = e2 + d.z, tot = e3 + d.w;
        int sc = tot;
        #pragma unroll
        for (int off = 1; off < 64; off <<= 1) {
            int u = __shfl_up(sc, off);
            if (ln >= off) sc += u;
        }
        if (ln == 63) wsum[wv] = sc;
        __syncthreads();
        if (wv == 0 && ln < 16) {
            int s2 = wsum[ln];
            #pragma unroll
            for (int off = 1; off < 16; off <<= 1) {
                int u = __shfl_up(s2, off);
                if (ln >= off) s2 += u;
            }
            wsum[ln] = s2;
        }
        __syncthreads();
        const int off0 = carry + ((wv > 0) ? wsum[wv - 1] : 0) + (sc - tot);
        if (i + 3 < N) {
            *(int4*)(rowptr + i) = make_int4(off0, off0 + e1, off0 + e2, off0 + e3);
        } else {
            if (i     < N) rowptr[i]     = off0;
            if (i + 1 < N) rowptr[i + 1] = off0 + e1;
            if (i + 2 < N) rowptr[i + 2] = off0 + e2;
        }
        carry += wsum[15];
        __syncthreads();
    }
    if (t == 0) rowptr[N] = carry;
}

__global__ __launch_bounds__(256)
void fill_csr(const int* __restrict__ src, const int* __restrict__ dst,
              const int* __restrict__ rowptr, const int* __restrict__ rank,
              int* __restrict__ csr, int E)
{
    int e4 = (blockIdx.x * 256 + threadIdx.x) * 4;
    if (e4 + 3 < E) {
        int4 d = *(const int4*)(dst + e4);
        int4 r = *(const int4*)(rank + e4);
        int4 s = *(const int4*)(src + e4);
        csr[rowptr[d.x] + r.x] = s.x;
        csr[rowptr[d.y] + r.y] = s.y;
        csr[rowptr[d.z] + r.z] = s.z;
        csr[rowptr[d.w] + r.w] = s.w;
    } else {
        for (int e = e4; e < E; ++e) csr[rowptr[dst[e]] + rank[e]] = src[e];
    }
}

// ---- gather-SUM only: 1 wave/node, 4 edges x 16 lanes x 16B in flight ------
// Writes raw sum (bf16 hi only) + ||sum||^2; all scalar math deferred.
__global__ __launch_bounds__(256)
void csr_gather_sum(const u16* __restrict__ ghi, const int* __restrict__ rowptr,
                    const int* __restrict__ csr, u16* __restrict__ ohi,
                    float* __restrict__ ssum, int N)
{
    int node = blockIdx.x * 4 + (threadIdx.x >> 6);
    if (node >= N) return;
    const int lane = threadIdx.x & 63;
    const int eg = lane >> 4, l15 = lane & 15;
    const int beg = rowptr[node], end = rowptr[node + 1];

    float acc[8] = {0.f,0.f,0.f,0.f,0.f,0.f,0.f,0.f};
    for (int b = beg; b < end; b += 64) {
        const int cnt = min(end - b, 64);
        const int myidx = (lane < cnt) ? csr[b + lane] : 0;
        u32x4 vc;
        {
            const bool act = eg < cnt;
            const int s = __shfl(myidx, act ? eg : 0);
            if (act) vc = *(const u32x4*)(ghi + (size_t)s * DD + l15 * 8);
        }
        for (int j = 0; j < cnt; j += 4) {
            const int en = j + 4 + eg;
            const bool actn = en < cnt;
            const int sn = __shfl(myidx, actn ? en : 0);
            u32x4 vn;
            if (actn) vn = *(const u32x4*)(ghi + (size_t)sn * DD + l15 * 8);
            if (j + eg < cnt) {
                #pragma unroll
                for (int p = 0; p < 4; ++p) {
                    acc[2*p+0] += __uint_as_float(vc[p] << 16);
                    acc[2*p+1] += __uint_as_float(vc[p] & 0xffff0000u);
                }
            }
            vc = vn;
        }
    }
    #pragma unroll
    for (int q = 0; q < 8; ++q) {
        acc[q] += __shfl_xor(acc[q], 16);
        acc[q] += __shfl_xor(acc[q], 32);
    }
    float ss = 0.f;
    #pragma unroll
    for (int q = 0; q < 8; ++q) ss += acc[q] * acc[q];
    ss += __shfl_xor(ss, 1); ss += __shfl_xor(ss, 2);
    ss += __shfl_xor(ss, 4); ss += __shfl_xor(ss, 8);
    if (eg == 0) {
        u32x4 hw;
        #pragma unroll
        for (int p = 0; p < 4; ++p) {
            u16 h0 = f2bf(acc[2*p+0]), h1 = f2bf(acc[2*p+1]);
            hw[p] = (unsigned)h0 | ((unsigned)h1 << 16);
        }
        *(u32x4*)(ohi + (size_t)node * DD + l15 * 8) = hw;
        if (l15 == 0) ssum[node] = ss;
    }
}

extern "C" void kernel_launch(void* const* d_in, const int* in_sizes, int n_in,
                              void* d_out, int out_size, void* d_ws, size_t ws_size,
                              hipStream_t stream)
{
    const float* x     = (const float*)d_in[0];
    const int*   ei    = (const int*)d_in[1];
    const float* msg_W = (const float*)d_in[2];
    const float* msg_b = (const float*)d_in[3];
    const float* upd_W = (const float*)d_in[4];
    const float* upd_b = (const float*)d_in[5];

    const int N = in_sizes[0] / DD;
    const int E = in_sizes[1] / 2;
    const int L = in_sizes[2] / (DD * DD);

    const int* src = ei;
    const int* dst = ei + E;

    // ws: A (sum hi) | W hi | W lo | deg(padded) | rowptr | csr | ssum
    u16* Ahi  = (u16*)d_ws;
    u16* WhiA = Ahi + (size_t)N * DD;
    u16* WloA = WhiA + (size_t)2 * L * DD * DD;
    int* deg  = (int*)(WloA + (size_t)2 * L * DD * DD);
    const int degCap = ((N + 4095) / 4096) * 4096;
    int* rowptr = deg + degCap;
    int* csr    = rowptr + (N + 1);
    float* ssum = (float*)(csr + E);

    // d_out hosts g (hi plane); second half holds rank[] during CSR build.
    u16* Bhi  = (u16*)d_out;
    int* rank = (int*)(Bhi + (size_t)N * DD);

    const int nodeBlocks  = (N + 63) / 64;
    const int aggBlocks   = (N + 3) / 4;
    const int edge4Blocks = ((E + 3) / 4 + 255) / 256;

    zero_int4<<<(degCap / 4 + 255) / 256, 256, 0, stream>>>((int4*)deg, degCap / 4);
    degree_rank<<<edge4Blocks, 256, 0, stream>>>(dst, deg, rank, E);
    scan_rowptr<<<1, 1024, 0, stream>>>(deg, rowptr, N);
    fill_csr<<<edge4Blocks, 256, 0, stream>>>(src, dst, rowptr, rank, csr, E);
    split_w<<<(2 * L * DD * DD + 255) / 256, 256, 0, stream>>>(
        msg_W, upd_W, WhiA, WloA, L);

    // K1 layer 0: g0 = chain(log0(x) @ Wm0^T + bm0) -> Bhi
    mfma_linear<1, 0, 1, 0><<<nodeBlocks, 256, 0, stream>>>(
        nullptr, x, nullptr, nullptr,
        WhiA, WloA, msg_b, Bhi, nullptr, N);

    for (int l = 0; l < L; ++l) {
        const u16* wuh = WhiA + (size_t)(l * 2 + 1) * DD * DD;
        const u16* wul = WloA + (size_t)(l * 2 + 1) * DD * DD;

        // gather: sum of g rows + ||sum||^2  (Bhi -> Ahi, ssum)
        csr_gather_sum<<<aggBlocks, 256, 0, stream>>>(
            Bhi, rowptr, csr, Ahi, ssum, N);

        if (l < L - 1) {
            // fused: update-linear(l) + message-linear(l+1) -> next g in Bhi
            const u16* wmh = WhiA + (size_t)((l + 1) * 2 + 0) * DD * DD;
            const u16* wml = WloA + (size_t)((l + 1) * 2 + 0) * DD * DD;
            mfma_linear_fused<<<nodeBlocks, 256, 0, stream>>>(
                Ahi, ssum, rowptr,
                wuh, wul, upd_b + (size_t)l * DD,
                wmh, wml, msg_b + (size_t)(l + 1) * DD,
                Bhi, N);
        } else {
            // final update-linear: manifold point, fp32 into d_out
            mfma_linear<0, 1, 0, 1><<<nodeBlocks, 256, 0, stream>>>(
                Ahi, nullptr, ssum, rowptr,
                wuh, wul, upd_b + (size_t)l * DD,
                nullptr, (float*)d_out, N);
        }
    }
}

// Round 18
// 227.410 us; speedup vs baseline: 1.2862x; 1.0433x over previous
//
#include <hip/hip_runtime.h>
#include <math.h>

#define EPSF 1e-5f
#define MAXN 0.95f
#define DD 128

typedef unsigned short u16;
typedef __attribute__((ext_vector_type(8))) __bf16 bf16x8;
typedef __attribute__((ext_vector_type(4))) float f32x4;
typedef __attribute__((ext_vector_type(8))) unsigned short u16x8;
typedef __attribute__((ext_vector_type(4))) unsigned u32x4;

#define MFMA16 __builtin_amdgcn_mfma_f32_16x16x32_bf16

__device__ __forceinline__ u16 f2bf(float f) {
    unsigned u = __float_as_uint(f);
    return (u16)((u + 0x7FFFu + ((u >> 16) & 1u)) >> 16);
}
__device__ __forceinline__ float bf2f(u16 b) {
    return __uint_as_float(((unsigned)b) << 16);
}

// exp0 -> proj -> (optional log0) collapses to one scalar factor of the row.
__device__ __forceinline__ float chain_scale(float nrm, bool log_out) {
    float nc  = fmaxf(nrm, EPSF);
    float f   = tanhf(nc) / nc;
    float wn  = f * nrm;
    float p   = (wn > MAXN) ? (MAXN / fmaxf(wn, EPSF)) : 1.f;
    float s   = f * p;
    if (log_out) {
        float n2  = wn * p;
        float n2c = fmaxf(n2, EPSF);
        float arg = fminf(n2c, 1.f - EPSF);
        s *= atanhf(arg) / n2c;
    }
    return s;
}

// folded per-node aggregate scalar: chain(||sum||/cnt, log)/cnt
__device__ __forceinline__ float agg_scale(const float* __restrict__ ssum,
                                           const int* __restrict__ rowptr,
                                           int rg) {
    int cnt = max(rowptr[rg + 1] - rowptr[rg], 1);
    float inv = 1.f / (float)cnt;
    return chain_scale(sqrtf(ssum[rg]) * inv, true) * inv;
}

// ---- merged prep: zero deg (blocks [0,zb)) + split W (blocks [zb, zb+sb)) --
__global__ __launch_bounds__(256)
void zero_split(int4* __restrict__ degz, int n4,
                const float* __restrict__ msgW, const float* __restrict__ updW,
                u16* __restrict__ whi, u16* __restrict__ wlo, int L, int zb)
{
    if ((int)blockIdx.x < zb) {
        int i = blockIdx.x * 256 + threadIdx.x;
        if (i < n4) degz[i] = make_int4(0, 0, 0, 0);
        return;
    }
    int gid = (blockIdx.x - zb) * 256 + threadIdx.x;
    int total = L * 2 * DD * DD;
    if (gid >= total) return;
    int mat = gid >> 14;
    int elem = gid & (DD * DD - 1);
    int l = mat >> 1, tpe = mat & 1;
    float f = (tpe ? updW : msgW)[(size_t)l * DD * DD + elem];
    u16 hb = f2bf(f);
    whi[gid] = hb;
    wlo[gid] = f2bf(f - bf2f(hb));
}

// ---- MERGED: degree_rank (blocks [0, eb)) + layer-0 K1 GEMM (blocks >= eb) -
// Independent work co-resident on the CUs: the GEMM's MFMA/VALU work hides
// the atomic blocks' L2-RMW latency (both were <16% pipe-busy standalone).
__global__ __launch_bounds__(256)
void k1_degree(const int* __restrict__ dst, int* __restrict__ deg,
               int* __restrict__ rank, int E, int eb,
               const float* __restrict__ xin,
               const u16* __restrict__ whi, const u16* __restrict__ wlo,
               const float* __restrict__ bias,
               u16* __restrict__ ohi, int N)
{
    __shared__ float sred[4][64];
    __shared__ float sScale[64];
    __shared__ u16 sHi[64][136];

    if ((int)blockIdx.x < eb) {
        // ---------------- degree + rank path ----------------
        int e4 = (blockIdx.x * 256 + threadIdx.x) * 4;
        if (e4 + 3 < E) {
            int4 d = *(const int4*)(dst + e4);
            int4 r;
            r.x = atomicAdd(&deg[d.x], 1);
            r.y = atomicAdd(&deg[d.y], 1);
            r.z = atomicAdd(&deg[d.z], 1);
            r.w = atomicAdd(&deg[d.w], 1);
            *(int4*)(rank + e4) = r;
        } else {
            for (int e = e4; e < E; ++e) rank[e] = atomicAdd(&deg[dst[e]], 1);
        }
        return;
    }

    // ---------------- K1 layer-0 GEMM path ----------------
    const int tid  = threadIdx.x;
    const int w    = tid >> 6;
    const int lane = tid & 63;
    const int l15  = lane & 15, lk = lane >> 4;
    const int base = (blockIdx.x - eb) * 64;

    bf16x8 wh[2][4], wl[2][4];
    #pragma unroll
    for (int nt = 0; nt < 2; ++nt) {
        const int j = w * 32 + nt * 16 + l15;
        #pragma unroll
        for (int kt = 0; kt < 4; ++kt) {
            const int off = j * DD + kt * 32 + lk * 8;
            wh[nt][kt] = *(const bf16x8*)(whi + off);
            wl[nt][kt] = *(const bf16x8*)(wlo + off);
        }
    }
    const float bv0 = bias[w * 32 + l15];
    const float bv1 = bias[w * 32 + 16 + l15];

    f32x4 acc[4][2];
    #pragma unroll
    for (int mt = 0; mt < 4; ++mt)
        #pragma unroll
        for (int nt = 0; nt < 2; ++nt)
            acc[mt][nt] = (f32x4){0.f, 0.f, 0.f, 0.f};

    #pragma unroll
    for (int mt = 0; mt < 4; ++mt) {
        int row = base + mt * 16 + l15;
        row = (row < N) ? row : (N - 1);
        const float* xr = xin + (size_t)row * DD + lk * 8;
        float fv[32];
        float ss = 0.f;
        #pragma unroll
        for (int kt = 0; kt < 4; ++kt) {
            float4 a = *(const float4*)(xr + kt * 32);
            float4 b = *(const float4*)(xr + kt * 32 + 4);
            fv[kt*8+0]=a.x; fv[kt*8+1]=a.y; fv[kt*8+2]=a.z; fv[kt*8+3]=a.w;
            fv[kt*8+4]=b.x; fv[kt*8+5]=b.y; fv[kt*8+6]=b.z; fv[kt*8+7]=b.w;
        }
        #pragma unroll
        for (int q = 0; q < 32; ++q) ss += fv[q] * fv[q];
        ss += __shfl_xor(ss, 16);
        ss += __shfl_xor(ss, 32);
        float nc = fmaxf(sqrtf(ss), EPSF);
        float sc = atanhf(fminf(nc, 1.f - EPSF)) / nc;
        bf16x8 ah[4];
        #pragma unroll
        for (int kt = 0; kt < 4; ++kt) {
            u16x8 uh;
            #pragma unroll
            for (int q = 0; q < 8; ++q)
                uh[q] = f2bf(fv[kt*8+q] * sc);
            ah[kt] = *reinterpret_cast<bf16x8*>(&uh);
        }
        #pragma unroll
        for (int kt = 0; kt < 4; ++kt) {
            #pragma unroll
            for (int nt = 0; nt < 2; ++nt) {
                acc[mt][nt] = MFMA16(ah[kt], wh[nt][kt], acc[mt][nt], 0, 0, 0);
                acc[mt][nt] = MFMA16(ah[kt], wl[nt][kt], acc[mt][nt], 0, 0, 0);
            }
        }
    }

    #pragma unroll
    for (int mt = 0; mt < 4; ++mt) {
        #pragma unroll
        for (int r = 0; r < 4; ++r) {
            float y0 = acc[mt][0][r] + bv0;
            float y1 = acc[mt][1][r] + bv1;
            float part = y0 * y0 + y1 * y1;
            part += __shfl_xor(part, 1);
            part += __shfl_xor(part, 2);
            part += __shfl_xor(part, 4);
            part += __shfl_xor(part, 8);
            if (l15 == 0) sred[w][mt*16 + lk*4 + r] = part;
        }
    }
    __syncthreads();
    if (tid < 64) {
        float ss = sred[0][tid] + sred[1][tid] + sred[2][tid] + sred[3][tid];
        sScale[tid] = chain_scale(sqrtf(ss), true);
    }
    __syncthreads();

    #pragma unroll
    for (int mt = 0; mt < 4; ++mt) {
        #pragma unroll
        for (int r = 0; r < 4; ++r) {
            const int rloc = mt*16 + lk*4 + r;
            const float s = sScale[rloc];
            #pragma unroll
            for (int nt = 0; nt < 2; ++nt) {
                float z = (acc[mt][nt][r] + (nt ? bv1 : bv0)) * s;
                sHi[rloc][w*32 + nt*16 + l15] = f2bf(z);
            }
        }
    }
    __syncthreads();
    const int row = tid >> 2, qc = (tid & 3) * 32;
    const int rg = base + row;
    if (rg < N) {
        #pragma unroll
        for (int i = 0; i < 4; ++i)
            *(u16x8*)(ohi + (size_t)rg * DD + qc + i*8) =
                *(const u16x8*)(&sHi[row][qc + i*8]);
    }
}

// ---- MFMA linear: out = chain( (s_agg?)*v @ W^T + b ) ----------------------
template<int LOG_OUT, int FP32_OUT, int F32_IN, int SCALE_IN>
__global__ __launch_bounds__(256)
void mfma_linear(const u16* __restrict__ vhi, const float* __restrict__ xin,
                 const float* __restrict__ ssum, const int* __restrict__ rowptr,
                 const u16* __restrict__ whi, const u16* __restrict__ wlo,
                 const float* __restrict__ bias,
                 u16* __restrict__ ohi, float* __restrict__ ofp, int N)
{
    __shared__ float sred[4][64];
    __shared__ float sScale[64];
    __shared__ float sSin[SCALE_IN ? 64 : 1];
    __shared__ u16 sHi[FP32_OUT ? 1 : 64][136];

    const int tid  = threadIdx.x;
    const int w    = tid >> 6;
    const int lane = tid & 63;
    const int l15  = lane & 15, lk = lane >> 4;
    const int base = blockIdx.x * 64;

    if (SCALE_IN) {
        if (tid < 64) {
            int rg = base + tid;
            sSin[tid] = agg_scale(ssum, rowptr, rg < N ? rg : (N - 1));
        }
        __syncthreads();
    }

    bf16x8 wh[2][4], wl[2][4];
    #pragma unroll
    for (int nt = 0; nt < 2; ++nt) {
        const int j = w * 32 + nt * 16 + l15;
        #pragma unroll
        for (int kt = 0; kt < 4; ++kt) {
            const int off = j * DD + kt * 32 + lk * 8;
            wh[nt][kt] = *(const bf16x8*)(whi + off);
            wl[nt][kt] = *(const bf16x8*)(wlo + off);
        }
    }
    const float bv0 = bias[w * 32 + l15];
    const float bv1 = bias[w * 32 + 16 + l15];

    f32x4 acc[4][2];
    #pragma unroll
    for (int mt = 0; mt < 4; ++mt)
        #pragma unroll
        for (int nt = 0; nt < 2; ++nt)
            acc[mt][nt] = (f32x4){0.f, 0.f, 0.f, 0.f};

    #pragma unroll
    for (int mt = 0; mt < 4; ++mt) {
        int row = base + mt * 16 + l15;
        row = (row < N) ? row : (N - 1);
        bf16x8 ah[4];
        if (F32_IN) {
            const float* xr = xin + (size_t)row * DD + lk * 8;
            float fv[32];
            float ss = 0.f;
            #pragma unroll
            for (int kt = 0; kt < 4; ++kt) {
                float4 a = *(const float4*)(xr + kt * 32);
                float4 b = *(const float4*)(xr + kt * 32 + 4);
                fv[kt*8+0]=a.x; fv[kt*8+1]=a.y; fv[kt*8+2]=a.z; fv[kt*8+3]=a.w;
                fv[kt*8+4]=b.x; fv[kt*8+5]=b.y; fv[kt*8+6]=b.z; fv[kt*8+7]=b.w;
            }
            #pragma unroll
            for (int q = 0; q < 32; ++q) ss += fv[q] * fv[q];
            ss += __shfl_xor(ss, 16);
            ss += __shfl_xor(ss, 32);
            float nc = fmaxf(sqrtf(ss), EPSF);
            float sc = atanhf(fminf(nc, 1.f - EPSF)) / nc;
            #pragma unroll
            for (int kt = 0; kt < 4; ++kt) {
                u16x8 uh;
                #pragma unroll
                for (int q = 0; q < 8; ++q)
                    uh[q] = f2bf(fv[kt*8+q] * sc);
                ah[kt] = *reinterpret_cast<bf16x8*>(&uh);
            }
        } else {
            const size_t ro = (size_t)row * DD + lk * 8;
            #pragma unroll
            for (int kt = 0; kt < 4; ++kt)
                ah[kt] = *(const bf16x8*)(vhi + ro + kt * 32);
        }
        #pragma unroll
        for (int kt = 0; kt < 4; ++kt) {
            #pragma unroll
            for (int nt = 0; nt < 2; ++nt) {
                acc[mt][nt] = MFMA16(ah[kt], wh[nt][kt], acc[mt][nt], 0, 0, 0);
                acc[mt][nt] = MFMA16(ah[kt], wl[nt][kt], acc[mt][nt], 0, 0, 0);
            }
        }
    }

    #pragma unroll
    for (int mt = 0; mt < 4; ++mt) {
        #pragma unroll
        for (int r = 0; r < 4; ++r) {
            const float sv = SCALE_IN ? sSin[mt*16 + lk*4 + r] : 1.f;
            float y0 = acc[mt][0][r] * sv + bv0;
            float y1 = acc[mt][1][r] * sv + bv1;
            float part = y0 * y0 + y1 * y1;
            part += __shfl_xor(part, 1);
            part += __shfl_xor(part, 2);
            part += __shfl_xor(part, 4);
            part += __shfl_xor(part, 8);
            if (l15 == 0) sred[w][mt*16 + lk*4 + r] = part;
        }
    }
    __syncthreads();
    if (tid < 64) {
        float ss = sred[0][tid] + sred[1][tid] + sred[2][tid] + sred[3][tid];
        sScale[tid] = chain_scale(sqrtf(ss), LOG_OUT != 0);
    }
    __syncthreads();

    #pragma unroll
    for (int mt = 0; mt < 4; ++mt) {
        #pragma unroll
        for (int r = 0; r < 4; ++r) {
            const int rloc = mt*16 + lk*4 + r;
            const float s = sScale[rloc];
            const float sv = SCALE_IN ? sSin[rloc] : 1.f;
            #pragma unroll
            for (int nt = 0; nt < 2; ++nt) {
                float z = (acc[mt][nt][r] * sv + (nt ? bv1 : bv0)) * s;
                const int col = w*32 + nt*16 + l15;
                if (FP32_OUT) {
                    const int rg = base + rloc;
                    if (rg < N) ofp[(size_t)rg * DD + col] = z;
                } else {
                    sHi[rloc][col] = f2bf(z);
                }
            }
        }
    }
    if (!FP32_OUT) {
        __syncthreads();
        const int row = tid >> 2, qc = (tid & 3) * 32;
        const int rg = base + row;
        if (rg < N) {
            #pragma unroll
            for (int i = 0; i < 4; ++i)
                *(u16x8*)(ohi + (size_t)rg * DD + qc + i*8) =
                    *(const u16x8*)(&sHi[row][qc + i*8]);
        }
    }
}

// ---- FUSED mid-boundary: g_{l+1} = chain( chain( s*v@Wu^T + bu ) @ Wm^T + bm )
__global__ __launch_bounds__(256)
void mfma_linear_fused(const u16* __restrict__ vhi,
                       const float* __restrict__ ssum, const int* __restrict__ rowptr,
                       const u16* __restrict__ wuh, const u16* __restrict__ wul,
                       const float* __restrict__ bu,
                       const u16* __restrict__ wmh, const u16* __restrict__ wml,
                       const float* __restrict__ bm,
                       u16* __restrict__ ohi, int N)
{
    __shared__ float sred[4][64];
    __shared__ float sScale[64];
    __shared__ float sSin[64];
    __shared__ u16 sHi[64][136];

    const int tid  = threadIdx.x;
    const int w    = tid >> 6;
    const int lane = tid & 63;
    const int l15  = lane & 15, lk = lane >> 4;
    const int base = blockIdx.x * 64;

    if (tid < 64) {
        int rg = base + tid;
        sSin[tid] = agg_scale(ssum, rowptr, rg < N ? rg : (N - 1));
    }
    __syncthreads();

    f32x4 acc[4][2];

    // ================= GEMM 1: t = chain( s*v @ Wu^T + bu ) =================
    {
        bf16x8 wh[2][4], wl[2][4];
        #pragma unroll
        for (int nt = 0; nt < 2; ++nt) {
            const int j = w * 32 + nt * 16 + l15;
            #pragma unroll
            for (int kt = 0; kt < 4; ++kt) {
                const int off = j * DD + kt * 32 + lk * 8;
                wh[nt][kt] = *(const bf16x8*)(wuh + off);
                wl[nt][kt] = *(const bf16x8*)(wul + off);
            }
        }
        const float bv0 = bu[w * 32 + l15];
        const float bv1 = bu[w * 32 + 16 + l15];

        #pragma unroll
        for (int mt = 0; mt < 4; ++mt)
            #pragma unroll
            for (int nt = 0; nt < 2; ++nt)
                acc[mt][nt] = (f32x4){0.f, 0.f, 0.f, 0.f};

        #pragma unroll
        for (int mt = 0; mt < 4; ++mt) {
            int row = base + mt * 16 + l15;
            row = (row < N) ? row : (N - 1);
            const size_t ro = (size_t)row * DD + lk * 8;
            bf16x8 ah[4];
            #pragma unroll
            for (int kt = 0; kt < 4; ++kt)
                ah[kt] = *(const bf16x8*)(vhi + ro + kt * 32);
            #pragma unroll
            for (int kt = 0; kt < 4; ++kt) {
                #pragma unroll
                for (int nt = 0; nt < 2; ++nt) {
                    acc[mt][nt] = MFMA16(ah[kt], wh[nt][kt], acc[mt][nt], 0, 0, 0);
                    acc[mt][nt] = MFMA16(ah[kt], wl[nt][kt], acc[mt][nt], 0, 0, 0);
                }
            }
        }

        #pragma unroll
        for (int mt = 0; mt < 4; ++mt) {
            #pragma unroll
            for (int r = 0; r < 4; ++r) {
                const float sv = sSin[mt*16 + lk*4 + r];
                float y0 = acc[mt][0][r] * sv + bv0;
                float y1 = acc[mt][1][r] * sv + bv1;
                float part = y0 * y0 + y1 * y1;
                part += __shfl_xor(part, 1);
                part += __shfl_xor(part, 2);
                part += __shfl_xor(part, 4);
                part += __shfl_xor(part, 8);
                if (l15 == 0) sred[w][mt*16 + lk*4 + r] = part;
            }
        }
        __syncthreads();
        if (tid < 64) {
            float ss = sred[0][tid] + sred[1][tid] + sred[2][tid] + sred[3][tid];
            sScale[tid] = chain_scale(sqrtf(ss), true);
        }
        __syncthreads();
        #pragma unroll
        for (int mt = 0; mt < 4; ++mt) {
            #pragma unroll
            for (int r = 0; r < 4; ++r) {
                const int rloc = mt*16 + lk*4 + r;
                const float s = sScale[rloc];
                const float sv = sSin[rloc];
                #pragma unroll
                for (int nt = 0; nt < 2; ++nt) {
                    float z = (acc[mt][nt][r] * sv + (nt ? bv1 : bv0)) * s;
                    sHi[rloc][w*32 + nt*16 + l15] = f2bf(z);
                }
            }
        }
    }
    __syncthreads();

    // ================= GEMM 2: g = chain( t @ Wm^T + bm ) ===================
    {
        bf16x8 wh[2][4], wl[2][4];
        #pragma unroll
        for (int nt = 0; nt < 2; ++nt) {
            const int j = w * 32 + nt * 16 + l15;
            #pragma unroll
            for (int kt = 0; kt < 4; ++kt) {
                const int off = j * DD + kt * 32 + lk * 8;
                wh[nt][kt] = *(const bf16x8*)(wmh + off);
                wl[nt][kt] = *(const bf16x8*)(wml + off);
            }
        }
        const float bv0 = bm[w * 32 + l15];
        const float bv1 = bm[w * 32 + 16 + l15];

        #pragma unroll
        for (int mt = 0; mt < 4; ++mt)
            #pragma unroll
            for (int nt = 0; nt < 2; ++nt)
                acc[mt][nt] = (f32x4){0.f, 0.f, 0.f, 0.f};

        #pragma unroll
        for (int mt = 0; mt < 4; ++mt) {
            const int r16 = mt * 16 + l15;
            bf16x8 ah[4];
            #pragma unroll
            for (int kt = 0; kt < 4; ++kt)
                ah[kt] = *(const bf16x8*)(&sHi[r16][kt * 32 + lk * 8]);
            #pragma unroll
            for (int kt = 0; kt < 4; ++kt) {
                #pragma unroll
                for (int nt = 0; nt < 2; ++nt) {
                    acc[mt][nt] = MFMA16(ah[kt], wh[nt][kt], acc[mt][nt], 0, 0, 0);
                    acc[mt][nt] = MFMA16(ah[kt], wl[nt][kt], acc[mt][nt], 0, 0, 0);
                }
            }
        }

        #pragma unroll
        for (int mt = 0; mt < 4; ++mt) {
            #pragma unroll
            for (int r = 0; r < 4; ++r) {
                float y0 = acc[mt][0][r] + bv0;
                float y1 = acc[mt][1][r] + bv1;
                float part = y0 * y0 + y1 * y1;
                part += __shfl_xor(part, 1);
                part += __shfl_xor(part, 2);
                part += __shfl_xor(part, 4);
                part += __shfl_xor(part, 8);
                if (l15 == 0) sred[w][mt*16 + lk*4 + r] = part;
            }
        }
        __syncthreads();
        if (tid < 64) {
            float ss = sred[0][tid] + sred[1][tid] + sred[2][tid] + sred[3][tid];
            sScale[tid] = chain_scale(sqrtf(ss), true);
        }
        __syncthreads();
        #pragma unroll
        for (int mt = 0; mt < 4; ++mt) {
            #pragma unroll
            for (int r = 0; r < 4; ++r) {
                const int rloc = mt*16 + lk*4 + r;
                const float s = sScale[rloc];
                #pragma unroll
                for (int nt = 0; nt < 2; ++nt) {
                    float z = (acc[mt][nt][r] + (nt ? bv1 : bv0)) * s;
                    sHi[rloc][w*32 + nt*16 + l15] = f2bf(z);
                }
            }
        }
        __syncthreads();
        const int row = tid >> 2, qc = (tid & 3) * 32;
        const int rg = base + row;
        if (rg < N) {
            #pragma unroll
            for (int i = 0; i < 4; ++i)
                *(u16x8*)(ohi + (size_t)rg * DD + qc + i*8) =
                    *(const u16x8*)(&sHi[row][qc + i*8]);
        }
    }
}

// ---------------- CSR build remainder ---------------------------------------
__global__ __launch_bounds__(1024)
void scan_rowptr(const int* __restrict__ deg, int* __restrict__ rowptr, int N)
{
    __shared__ int wsum[16];
    const int t = threadIdx.x, wv = t >> 6, ln = t & 63;
    int carry = 0;
    const int nch = (N + 4095) / 4096;
    for (int c = 0; c < nch; ++c) {
        const int i = c * 4096 + t * 4;
        int4 d = *(const int4*)(deg + i);
        int e1 = d.x, e2 = e1 + d.y, e3 = e2 + d.z, tot = e3 + d.w;
        int sc = tot;
        #pragma unroll
        for (int off = 1; off < 64; off <<= 1) {
            int u = __shfl_up(sc, off);
            if (ln >= off) sc += u;
        }
        if (ln == 63) wsum[wv] = sc;
        __syncthreads();
        if (wv == 0 && ln < 16) {
            int s2 = wsum[ln];
            #pragma unroll
            for (int off = 1; off < 16; off <<= 1) {
                int u = __shfl_up(s2, off);
                if (ln >= off) s2 += u;
            }
            wsum[ln] = s2;
        }
        __syncthreads();
        const int off0 = carry + ((wv > 0) ? wsum[wv - 1] : 0) + (sc - tot);
        if (i + 3 < N) {
            *(int4*)(rowptr + i) = make_int4(off0, off0 + e1, off0 + e2, off0 + e3);
        } else {
            if (i     < N) rowptr[i]     = off0;
            if (i + 1 < N) rowptr[i + 1] = off0 + e1;
            if (i + 2 < N) rowptr[i + 2] = off0 + e2;
        }
        carry += wsum[15];
        __syncthreads();
    }
    if (t == 0) rowptr[N] = carry;
}

__global__ __launch_bounds__(256)
void fill_csr(const int* __restrict__ src, const int* __restrict__ dst,
              const int* __restrict__ rowptr, const int* __restrict__ rank,
              int* __restrict__ csr, int E)
{
    int e4 = (blockIdx.x * 256 + threadIdx.x) * 4;
    if (e4 + 3 < E) {
        int4 d = *(const int4*)(dst + e4);
        int4 r = *(const int4*)(rank + e4);
        int4 s = *(const int4*)(src + e4);
        csr[rowptr[d.x] + r.x] = s.x;
        csr[rowptr[d.y] + r.y] = s.y;
        csr[rowptr[d.z] + r.z] = s.z;
        csr[rowptr[d.w] + r.w] = s.w;
    } else {
        for (int e = e4; e < E; ++e) csr[rowptr[dst[e]] + rank[e]] = src[e];
    }
}

// ---- gather-SUM only: 1 wave/node, 4 edges x 16 lanes x 16B in flight ------
__global__ __launch_bounds__(256)
void csr_gather_sum(const u16* __restrict__ ghi, const int* __restrict__ rowptr,
                    const int* __restrict__ csr, u16* __restrict__ ohi,
                    float* __restrict__ ssum, int N)
{
    int node = blockIdx.x * 4 + (threadIdx.x >> 6);
    if (node >= N) return;
    const int lane = threadIdx.x & 63;
    const int eg = lane >> 4, l15 = lane & 15;
    const int beg = rowptr[node], end = rowptr[node + 1];

    float acc[8] = {0.f,0.f,0.f,0.f,0.f,0.f,0.f,0.f};
    for (int b = beg; b < end; b += 64) {
        const int cnt = min(end - b, 64);
        const int myidx = (lane < cnt) ? csr[b + lane] : 0;
        u32x4 vc;
        {
            const bool act = eg < cnt;
            const int s = __shfl(myidx, act ? eg : 0);
            if (act) vc = *(const u32x4*)(ghi + (size_t)s * DD + l15 * 8);
        }
        for (int j = 0; j < cnt; j += 4) {
            const int en = j + 4 + eg;
            const bool actn = en < cnt;
            const int sn = __shfl(myidx, actn ? en : 0);
            u32x4 vn;
            if (actn) vn = *(const u32x4*)(ghi + (size_t)sn * DD + l15 * 8);
            if (j + eg < cnt) {
                #pragma unroll
                for (int p = 0; p < 4; ++p) {
                    acc[2*p+0] += __uint_as_float(vc[p] << 16);
                    acc[2*p+1] += __uint_as_float(vc[p] & 0xffff0000u);
                }
            }
            vc = vn;
        }
    }
    #pragma unroll
    for (int q = 0; q < 8; ++q) {
        acc[q] += __shfl_xor(acc[q], 16);
        acc[q] += __shfl_xor(acc[q], 32);
    }
    float ss = 0.f;
    #pragma unroll
    for (int q = 0; q < 8; ++q) ss += acc[q] * acc[q];
    ss += __shfl_xor(ss, 1); ss += __shfl_xor(ss, 2);
    ss += __shfl_xor(ss, 4); ss += __shfl_xor(ss, 8);
    if (eg == 0) {
        u32x4 hw;
        #pragma unroll
        for (int p = 0; p < 4; ++p) {
            u16 h0 = f2bf(acc[2*p+0]), h1 = f2bf(acc[2*p+1]);
            hw[p] = (unsigned)h0 | ((unsigned)h1 << 16);
        }
        *(u32x4*)(ohi + (size_t)node * DD + l15 * 8) = hw;
        if (l15 == 0) ssum[node] = ss;
    }
}

extern "C" void kernel_launch(void* const* d_in, const int* in_sizes, int n_in,
                              void* d_out, int out_size, void* d_ws, size_t ws_size,
                              hipStream_t stream)
{
    const float* x     = (const float*)d_in[0];
    const int*   ei    = (const int*)d_in[1];
    const float* msg_W = (const float*)d_in[2];
    const float* msg_b = (const float*)d_in[3];
    const float* upd_W = (const float*)d_in[4];
    const float* upd_b = (const float*)d_in[5];

    const int N = in_sizes[0] / DD;
    const int E = in_sizes[1] / 2;
    const int L = in_sizes[2] / (DD * DD);

    const int* src = ei;
    const int* dst = ei + E;

    // ws: A (sum hi) | W hi | W lo | deg(padded) | rowptr | csr | ssum
    u16* Ahi  = (u16*)d_ws;
    u16* WhiA = Ahi + (size_t)N * DD;
    u16* WloA = WhiA + (size_t)2 * L * DD * DD;
    int* deg  = (int*)(WloA + (size_t)2 * L * DD * DD);
    const int degCap = ((N + 4095) / 4096) * 4096;
    int* rowptr = deg + degCap;
    int* csr    = rowptr + (N + 1);
    float* ssum = (float*)(csr + E);

    // d_out hosts g (hi plane); second half holds rank[] during CSR build.
    u16* Bhi  = (u16*)d_out;
    int* rank = (int*)(Bhi + (size_t)N * DD);

    const int nodeBlocks  = (N + 63) / 64;
    const int aggBlocks   = (N + 3) / 4;
    const int edge4Blocks = ((E + 3) / 4 + 255) / 256;
    const int zeroBlocks  = (degCap / 4 + 255) / 256;
    const int splitBlocks = (2 * L * DD * DD + 255) / 256;

    // merged prep: zero deg || split W  (independent writes)
    zero_split<<<zeroBlocks + splitBlocks, 256, 0, stream>>>(
        (int4*)deg, degCap / 4, msg_W, upd_W, WhiA, WloA, L, zeroBlocks);

    // merged: degree_rank || K1 layer-0 GEMM (independent; co-resident)
    k1_degree<<<edge4Blocks + nodeBlocks, 256, 0, stream>>>(
        dst, deg, rank, E, edge4Blocks,
        x, WhiA, WloA, msg_b, Bhi, N);

    scan_rowptr<<<1, 1024, 0, stream>>>(deg, rowptr, N);
    fill_csr<<<edge4Blocks, 256, 0, stream>>>(src, dst, rowptr, rank, csr, E);

    for (int l = 0; l < L; ++l) {
        const u16* wuh = WhiA + (size_t)(l * 2 + 1) * DD * DD;
        const u16* wul = WloA + (size_t)(l * 2 + 1) * DD * DD;

        // gather: sum of g rows + ||sum||^2  (Bhi -> Ahi, ssum)
        csr_gather_sum<<<aggBlocks, 256, 0, stream>>>(
            Bhi, rowptr, csr, Ahi, ssum, N);

        if (l < L - 1) {
            const u16* wmh = WhiA + (size_t)((l + 1) * 2 + 0) * DD * DD;
            const u16* wml = WloA + (size_t)((l + 1) * 2 + 0) * DD * DD;
            mfma_linear_fused<<<nodeBlocks, 256, 0, stream>>>(
                Ahi, ssum, rowptr,
                wuh, wul, upd_b + (size_t)l * DD,
                wmh, wml, msg_b + (size_t)(l + 1) * DD,
                Bhi, N);
        } else {
            mfma_linear<0, 1, 0, 1><<<nodeBlocks, 256, 0, stream>>>(
                Ahi, nullptr, ssum, rowptr,
                wuh, wul, upd_b + (size_t)l * DD,
                nullptr, (float*)d_out, N);
        }
    }
}